// Round 1
// baseline (387.137 us; speedup 1.0000x reference)
//
#include <hip/hip_runtime.h>
#include <hip/hip_bf16.h>
#include <float.h>

#define SS 4096
#define EE 64
#define DD 4096
#define CAP 128
#define SE (SS*EE)                    // 262144
static const size_t SEC = (size_t)SS * EE * CAP;  // 33554432

typedef unsigned long long u64;
typedef unsigned int u32;

// ---------------- W transpose: Wt[k][e] = W[e][k] ----------------
__global__ __launch_bounds__(256) void k_transpose(const float* __restrict__ W,
                                                   float* __restrict__ Wt) {
  __shared__ float t[64][65];
  int k0 = blockIdx.x * 64;
  int tid = threadIdx.x;
#pragma unroll
  for (int i = 0; i < 4; i++) {
    int f = tid + i * 256;
    int e = f >> 4, c4 = f & 15;
    float4 v = *(const float4*)(W + (size_t)e * DD + k0 + c4 * 4);
    t[e][c4 * 4 + 0] = v.x; t[e][c4 * 4 + 1] = v.y;
    t[e][c4 * 4 + 2] = v.z; t[e][c4 * 4 + 3] = v.w;
  }
  __syncthreads();
#pragma unroll
  for (int i = 0; i < 4; i++) {
    int f = tid + i * 256;
    int r = f >> 4, e4 = f & 15;
    float4 o;
    o.x = t[e4 * 4 + 0][r]; o.y = t[e4 * 4 + 1][r];
    o.z = t[e4 * 4 + 2][r]; o.w = t[e4 * 4 + 3][r];
    *(float4*)(Wt + (size_t)(k0 + r) * 64 + e4 * 4) = o;
  }
}

// ---------------- GEMM: part[ks][t][e] = sum_{k in slice} x[t][k]*Wt[k][e] ----------------
__global__ __launch_bounds__(256) void k_gemm(const float* __restrict__ x,
                                              const float* __restrict__ Wt,
                                              float* __restrict__ part) {
  __shared__ float xs[64][68];   // padded rows: conflict-free scalar/vec reads
  __shared__ float wsh[64][64];  // [k][e] linear: float4-over-e reads are conflict-free
  int tb = blockIdx.x;  // token tile (64 tokens)
  int ks = blockIdx.y;  // k slice (1024 wide)
  int tid = threadIdx.x;
  int tx = tid & 15, ty = tid >> 4;  // tx -> expert quad, ty -> token quad
  float acc[4][4] = {};
  for (int kc = 0; kc < 1024; kc += 64) {
    int k0 = ks * 1024 + kc;
#pragma unroll
    for (int i = 0; i < 4; i++) {
      int f = tid + i * 256;
      int r = f >> 4, c4 = f & 15;
      float4 v = *(const float4*)(x + (size_t)(tb * 64 + r) * DD + k0 + c4 * 4);
      xs[r][c4 * 4 + 0] = v.x; xs[r][c4 * 4 + 1] = v.y;
      xs[r][c4 * 4 + 2] = v.z; xs[r][c4 * 4 + 3] = v.w;
    }
#pragma unroll
    for (int i = 0; i < 4; i++) {
      int f = tid + i * 256;
      int r = f >> 4, c4 = f & 15;
      *(float4*)&wsh[r][c4 * 4] = *(const float4*)(Wt + (size_t)(k0 + r) * 64 + c4 * 4);
    }
    __syncthreads();
#pragma unroll 4
    for (int k4 = 0; k4 < 16; k4++) {
      float xa[4][4], wa[4][4];
#pragma unroll
      for (int i = 0; i < 4; i++) {
        float4 v = *(const float4*)&xs[ty * 4 + i][k4 * 4];
        xa[i][0] = v.x; xa[i][1] = v.y; xa[i][2] = v.z; xa[i][3] = v.w;
      }
#pragma unroll
      for (int kk = 0; kk < 4; kk++) {
        float4 v = *(const float4*)&wsh[k4 * 4 + kk][tx * 4];
        wa[kk][0] = v.x; wa[kk][1] = v.y; wa[kk][2] = v.z; wa[kk][3] = v.w;
      }
#pragma unroll
      for (int i = 0; i < 4; i++)
#pragma unroll
        for (int j = 0; j < 4; j++)
          acc[i][j] += xa[i][0] * wa[0][j] + xa[i][1] * wa[1][j]
                     + xa[i][2] * wa[2][j] + xa[i][3] * wa[3][j];
    }
    __syncthreads();
  }
#pragma unroll
  for (int i = 0; i < 4; i++) {
    float4 o = make_float4(acc[i][0], acc[i][1], acc[i][2], acc[i][3]);
    *(float4*)(part + ((size_t)ks * SS + tb * 64 + ty * 4 + i) * 64 + tx * 4) = o;
  }
}

// ---------------- per-token: softmax, top1 (gates), 2nd (logits), key ----------------
__global__ __launch_bounds__(64) void k_row(const float* __restrict__ part,
                                            const float* __restrict__ bias,
                                            float* __restrict__ gates,
                                            u64* __restrict__ keys,
                                            float2* __restrict__ g12,
                                            u32* __restrict__ cnt1) {
  int t = blockIdx.x;
  int e = threadIdx.x;
  size_t i = (size_t)t * 64 + e;
  float l = part[i] + part[i + (size_t)SE] + part[i + 2 * (size_t)SE]
          + part[i + 3 * (size_t)SE] + bias[e];
  // row max (value only) for stable softmax
  float m = l;
#pragma unroll
  for (int off = 32; off; off >>= 1) m = fmaxf(m, __shfl_xor(m, off));
  float ex = expf(l - m);
  float Z = ex;
#pragma unroll
  for (int off = 32; off; off >>= 1) Z += __shfl_xor(Z, off);
  float gate = ex / Z;
  gates[i] = gate;
  // argmax over gates, first-index tiebreak (== jnp.argmax)
  float v1 = gate; int i1 = e;
#pragma unroll
  for (int off = 32; off; off >>= 1) {
    float ov = __shfl_xor(v1, off); int oi = __shfl_xor(i1, off);
    if (ov > v1 || (ov == v1 && oi < i1)) { v1 = ov; i1 = oi; }
  }
  // 2nd-largest logit excluding i1, first-index tiebreak (== stable argsort(-logits)[1])
  float v2 = (e == i1) ? -FLT_MAX : l; int i2 = e;
#pragma unroll
  for (int off = 32; off; off >>= 1) {
    float ov = __shfl_xor(v2, off); int oi = __shfl_xor(i2, off);
    if (ov > v2 || (ov == v2 && oi < i2)) { v2 = ov; i2 = oi; }
  }
  float g1v = __shfl(gate, i1);
  float g2v = __shfl(gate, i2);
  if (e == 0) {
    u32 gb = __float_as_uint(v1);  // v1 = max gate (>0) -> bits monotone
    keys[t] = ((u64)(~gb) << 32) | ((u32)t << 12) | ((u32)i1 << 6) | (u32)i2;
    g12[t] = make_float2(g1v, g2v);
    atomicAdd(&cnt1[i1], 1u);
  }
}

// ---------------- pairwise rank counting ----------------
// r1[t] = #{s: e1[s]==e1[t] && key[s]<key[t]}   (priority rank within expert-1)
// r2[t] = #{s<t: e2[s]==e2[t]}                  (plain cumsum rank within expert-2)
__global__ __launch_bounds__(256) void k_pair(const u64* __restrict__ keys,
                                              u32* __restrict__ r1a,
                                              u32* __restrict__ r2a) {
  __shared__ u64 sk[256];
  int tid = threadIdx.x;
  int t = blockIdx.x * 256 + tid;
  sk[tid] = keys[blockIdx.y * 256 + tid];
  __syncthreads();
  u64 myk = keys[t];
  u32 mye1 = (u32)((myk >> 6) & 63), mye2 = (u32)(myk & 63);
  u32 myt = (u32)t;
  u32 r1 = 0, r2 = 0;
  for (int j = 0; j < 256; j++) {
    u64 ks = sk[j];
    u32 se1 = (u32)((ks >> 6) & 63);
    u32 se2 = (u32)(ks & 63);
    u32 ss = (u32)((ks >> 12) & 4095);
    r1 += (se1 == mye1 && ks < myk) ? 1u : 0u;
    r2 += (se2 == mye2 && ss < myt) ? 1u : 0u;
  }
  if (r1) atomicAdd(&r1a[t], r1);
  if (r2) atomicAdd(&r2a[t], r2);
}

// ---------------- load-balance aux loss ----------------
__global__ __launch_bounds__(256) void k_laux(const float* __restrict__ gates,
                                              const u32* __restrict__ cnt1,
                                              float* __restrict__ out) {
  __shared__ float sh[256];
  int tid = threadIdx.x;
  int e = tid & 63, q = tid >> 6;
  float s = 0.f;
  for (int r = q; r < SS; r += 4) s += gates[(size_t)r * 64 + e];
  sh[tid] = s;
  __syncthreads();
  if (tid < 64) {
    float v = sh[tid] + sh[tid + 64] + sh[tid + 128] + sh[tid + 192];
    float me = v * (1.0f / SS);
    float ce = (float)cnt1[tid] * (1.0f / SS);
    float term = me * ce;
#pragma unroll
    for (int off = 32; off; off >>= 1) term += __shfl_xor(term, off);
    if (tid == 0) out[0] = term * (float)EE * 0.01f;
  }
}

// ---------------- final scatter into combine / dispatch ----------------
__global__ __launch_bounds__(256) void k_final(const u64* __restrict__ keys,
                                               const float2* __restrict__ g12,
                                               const u32* __restrict__ cnt1,
                                               const u32* __restrict__ r1a,
                                               const u32* __restrict__ r2a,
                                               float* __restrict__ out) {
  int t = blockIdx.x * 256 + threadIdx.x;
  u64 k = keys[t];
  int e1 = (int)((k >> 6) & 63), e2 = (int)(k & 63);
  u32 r1 = r1a[t];
  u32 loc2 = cnt1[e2] + r2a[t];
  float2 g = g12[t];
  bool k1 = r1 < (u32)CAP;
  bool k2 = loc2 < (u32)CAP;
  float g1 = k1 ? g.x : 0.f;
  float g2 = k2 ? g.y : 0.f;
  float den = fmaxf(g1 + g2, 1.1920929e-07f);  // np.finfo(f32).eps
  float c1 = g1 / den, c2 = g2 / den;
  float* comb = out + 1;
  float* disp = out + 1 + SEC;
  if (k1) {
    size_t o = ((size_t)t * 64 + e1) * CAP + r1;
    comb[o] = c1;
    disp[o] = 1.0f;
  }
  if (k2) {
    size_t o = ((size_t)t * 64 + e2) * CAP + loc2;
    comb[o] = c2;
    disp[o] = 1.0f;
  }
}

extern "C" void kernel_launch(void* const* d_in, const int* in_sizes, int n_in,
                              void* d_out, int out_size, void* d_ws, size_t ws_size,
                              hipStream_t stream) {
  const float* x = (const float*)d_in[0];
  const float* W = (const float*)d_in[1];
  const float* bias = (const float*)d_in[2];
  float* out = (float*)d_out;

  // workspace layout
  float* Wt = (float*)d_ws;                 // 262144 floats (1 MB)
  float* part = Wt + 262144;                // 4*SS*EE floats (4 MB)
  float* gates = part + 4 * (size_t)SE;     // 262144 floats (1 MB)
  u64* keys = (u64*)(gates + (size_t)SE);   // 4096 u64
  float2* g12 = (float2*)(keys + SS);       // 4096 float2
  u32* cnt1 = (u32*)(g12 + SS);             // 64
  u32* r1a = cnt1 + 64;                     // 4096
  u32* r2a = r1a + SS;                      // 4096

  hipMemsetAsync(d_out, 0, (size_t)out_size * sizeof(float), stream);
  hipMemsetAsync(cnt1, 0, (64 + 2 * SS) * sizeof(u32), stream);

  k_transpose<<<64, 256, 0, stream>>>(W, Wt);
  k_gemm<<<dim3(64, 4), 256, 0, stream>>>(x, Wt, part);
  k_row<<<SS, 64, 0, stream>>>(part, bias, gates, keys, g12, cnt1);
  k_pair<<<dim3(16, 16), 256, 0, stream>>>(keys, r1a, r2a);
  k_laux<<<1, 256, 0, stream>>>(gates, cnt1, out);
  k_final<<<16, 256, 0, stream>>>(keys, g12, cnt1, r1a, r2a, out);
}

// Round 2
// 152.468 us; speedup vs baseline: 2.5391x; 2.5391x over previous
//
#include <hip/hip_runtime.h>
#include <hip/hip_bf16.h>
#include <float.h>

#define SS 4096
#define EE 64
#define DD 4096
#define CAP 128
#define SE (SS*EE)                    // 262144
static const size_t SEC = (size_t)SS * EE * CAP;  // 33554432

typedef unsigned long long u64;
typedef unsigned int u32;

// ---------------- W transpose: Wt[k][e] = W[e][k] ----------------
__global__ __launch_bounds__(256) void k_transpose(const float* __restrict__ W,
                                                   float* __restrict__ Wt) {
  __shared__ float t[64][65];
  int k0 = blockIdx.x * 64;
  int tid = threadIdx.x;
#pragma unroll
  for (int i = 0; i < 4; i++) {
    int f = tid + i * 256;
    int e = f >> 4, c4 = f & 15;
    float4 v = *(const float4*)(W + (size_t)e * DD + k0 + c4 * 4);
    t[e][c4 * 4 + 0] = v.x; t[e][c4 * 4 + 1] = v.y;
    t[e][c4 * 4 + 2] = v.z; t[e][c4 * 4 + 3] = v.w;
  }
  __syncthreads();
#pragma unroll
  for (int i = 0; i < 4; i++) {
    int f = tid + i * 256;
    int r = f >> 4, e4 = f & 15;
    float4 o;
    o.x = t[e4 * 4 + 0][r]; o.y = t[e4 * 4 + 1][r];
    o.z = t[e4 * 4 + 2][r]; o.w = t[e4 * 4 + 3][r];
    *(float4*)(Wt + (size_t)(k0 + r) * 64 + e4 * 4) = o;
  }
}

// ---------------- GEMM: part[ks][t][e] = sum_{k in slice} x[t][k]*Wt[k][e] ----------------
__global__ __launch_bounds__(256) void k_gemm(const float* __restrict__ x,
                                              const float* __restrict__ Wt,
                                              float* __restrict__ part) {
  __shared__ float xs[64][68];   // padded rows: conflict-free scalar/vec reads
  __shared__ float wsh[64][64];  // [k][e] linear: float4-over-e reads are conflict-free
  int tb = blockIdx.x;  // token tile (64 tokens)
  int ks = blockIdx.y;  // k slice (1024 wide)
  int tid = threadIdx.x;
  int tx = tid & 15, ty = tid >> 4;  // tx -> expert quad, ty -> token quad
  float acc[4][4] = {};
  for (int kc = 0; kc < 1024; kc += 64) {
    int k0 = ks * 1024 + kc;
#pragma unroll
    for (int i = 0; i < 4; i++) {
      int f = tid + i * 256;
      int r = f >> 4, c4 = f & 15;
      float4 v = *(const float4*)(x + (size_t)(tb * 64 + r) * DD + k0 + c4 * 4);
      xs[r][c4 * 4 + 0] = v.x; xs[r][c4 * 4 + 1] = v.y;
      xs[r][c4 * 4 + 2] = v.z; xs[r][c4 * 4 + 3] = v.w;
    }
#pragma unroll
    for (int i = 0; i < 4; i++) {
      int f = tid + i * 256;
      int r = f >> 4, c4 = f & 15;
      *(float4*)&wsh[r][c4 * 4] = *(const float4*)(Wt + (size_t)(k0 + r) * 64 + c4 * 4);
    }
    __syncthreads();
#pragma unroll 4
    for (int k4 = 0; k4 < 16; k4++) {
      float xa[4][4], wa[4][4];
#pragma unroll
      for (int i = 0; i < 4; i++) {
        float4 v = *(const float4*)&xs[ty * 4 + i][k4 * 4];
        xa[i][0] = v.x; xa[i][1] = v.y; xa[i][2] = v.z; xa[i][3] = v.w;
      }
#pragma unroll
      for (int kk = 0; kk < 4; kk++) {
        float4 v = *(const float4*)&wsh[k4 * 4 + kk][tx * 4];
        wa[kk][0] = v.x; wa[kk][1] = v.y; wa[kk][2] = v.z; wa[kk][3] = v.w;
      }
#pragma unroll
      for (int i = 0; i < 4; i++)
#pragma unroll
        for (int j = 0; j < 4; j++)
          acc[i][j] += xa[i][0] * wa[0][j] + xa[i][1] * wa[1][j]
                     + xa[i][2] * wa[2][j] + xa[i][3] * wa[3][j];
    }
    __syncthreads();
  }
#pragma unroll
  for (int i = 0; i < 4; i++) {
    float4 o = make_float4(acc[i][0], acc[i][1], acc[i][2], acc[i][3]);
    *(float4*)(part + ((size_t)ks * SS + tb * 64 + ty * 4 + i) * 64 + tx * 4) = o;
  }
}

// ---------------- per-token: softmax, top1 (gates), 2nd (logits), key ----------------
__global__ __launch_bounds__(64) void k_row(const float* __restrict__ part,
                                            const float* __restrict__ bias,
                                            float* __restrict__ gates,
                                            u64* __restrict__ keys,
                                            float2* __restrict__ g12,
                                            u32* __restrict__ cnt1) {
  int t = blockIdx.x;
  int e = threadIdx.x;
  size_t i = (size_t)t * 64 + e;
  float l = part[i] + part[i + (size_t)SE] + part[i + 2 * (size_t)SE]
          + part[i + 3 * (size_t)SE] + bias[e];
  // row max (value only) for stable softmax
  float m = l;
#pragma unroll
  for (int off = 32; off; off >>= 1) m = fmaxf(m, __shfl_xor(m, off));
  float ex = expf(l - m);
  float Z = ex;
#pragma unroll
  for (int off = 32; off; off >>= 1) Z += __shfl_xor(Z, off);
  float gate = ex / Z;
  gates[i] = gate;
  // argmax over gates, first-index tiebreak (== jnp.argmax)
  float v1 = gate; int i1 = e;
#pragma unroll
  for (int off = 32; off; off >>= 1) {
    float ov = __shfl_xor(v1, off); int oi = __shfl_xor(i1, off);
    if (ov > v1 || (ov == v1 && oi < i1)) { v1 = ov; i1 = oi; }
  }
  // 2nd-largest logit excluding i1, first-index tiebreak (== stable argsort(-logits)[1])
  float v2 = (e == i1) ? -FLT_MAX : l; int i2 = e;
#pragma unroll
  for (int off = 32; off; off >>= 1) {
    float ov = __shfl_xor(v2, off); int oi = __shfl_xor(i2, off);
    if (ov > v2 || (ov == v2 && oi < i2)) { v2 = ov; i2 = oi; }
  }
  float g1v = __shfl(gate, i1);
  float g2v = __shfl(gate, i2);
  if (e == 0) {
    u32 gb = __float_as_uint(v1);  // v1 = max gate (>0) -> bits monotone
    keys[t] = ((u64)(~gb) << 32) | ((u32)t << 12) | ((u32)i1 << 6) | (u32)i2;
    g12[t] = make_float2(g1v, g2v);
    atomicAdd(&cnt1[i1], 1u);
  }
}

// ---------------- pairwise rank counting ----------------
// r1[t] = #{s: e1[s]==e1[t] && key[s]<key[t]}   (priority rank within expert-1)
// r2[t] = #{s<t: e2[s]==e2[t]}                  (plain cumsum rank within expert-2)
__global__ __launch_bounds__(256) void k_pair(const u64* __restrict__ keys,
                                              u32* __restrict__ r1a,
                                              u32* __restrict__ r2a) {
  __shared__ u64 sk[256];
  int tid = threadIdx.x;
  int t = blockIdx.x * 256 + tid;
  sk[tid] = keys[blockIdx.y * 256 + tid];
  __syncthreads();
  u64 myk = keys[t];
  u32 mye1 = (u32)((myk >> 6) & 63), mye2 = (u32)(myk & 63);
  u32 myt = (u32)t;
  u32 r1 = 0, r2 = 0;
  for (int j = 0; j < 256; j++) {
    u64 ks = sk[j];
    u32 se1 = (u32)((ks >> 6) & 63);
    u32 se2 = (u32)(ks & 63);
    u32 ss = (u32)((ks >> 12) & 4095);
    r1 += (se1 == mye1 && ks < myk) ? 1u : 0u;
    r2 += (se2 == mye2 && ss < myt) ? 1u : 0u;
  }
  if (r1) atomicAdd(&r1a[t], r1);
  if (r2) atomicAdd(&r2a[t], r2);
}

// ---------------- gates column partial sums (deterministic, coalesced) ----------------
// block b covers tokens [b*64, b*64+64); wave w sums 16 tokens; lane = expert.
__global__ __launch_bounds__(256) void k_colsum(const float* __restrict__ gates,
                                                float* __restrict__ partial) {
  __shared__ float sh[256];
  int b = blockIdx.x;
  int tid = threadIdx.x;
  int lane = tid & 63, w = tid >> 6;
  float s = 0.f;
#pragma unroll
  for (int i = 0; i < 16; i++) {
    int t = b * 64 + w * 16 + i;
    s += gates[(size_t)t * 64 + lane];
  }
  sh[tid] = s;
  __syncthreads();
  if (tid < 64) {
    float p = sh[tid] + sh[tid + 64] + sh[tid + 128] + sh[tid + 192];
    partial[b * 64 + tid] = p;
  }
}

// ---------------- final l_aux combine (1 block, deterministic) ----------------
__global__ __launch_bounds__(256) void k_laux2(const float* __restrict__ partial,
                                               const u32* __restrict__ cnt1,
                                               float* __restrict__ out) {
  __shared__ float sh[256];
  int tid = threadIdx.x;
  int e = tid & 63, q = tid >> 6;
  float s = 0.f;
#pragma unroll
  for (int b = 0; b < 16; b++) s += partial[(q * 16 + b) * 64 + e];
  sh[tid] = s;
  __syncthreads();
  if (tid < 64) {
    float colsum = sh[tid] + sh[tid + 64] + sh[tid + 128] + sh[tid + 192];
    float me = colsum * (1.0f / SS);
    float ce = (float)cnt1[tid] * (1.0f / SS);
    float term = me * ce;
#pragma unroll
    for (int off = 32; off; off >>= 1) term += __shfl_xor(term, off);
    if (tid == 0) out[0] = term * (float)EE * 0.01f;
  }
}

// ---------------- final scatter into combine / dispatch ----------------
__global__ __launch_bounds__(256) void k_final(const u64* __restrict__ keys,
                                               const float2* __restrict__ g12,
                                               const u32* __restrict__ cnt1,
                                               const u32* __restrict__ r1a,
                                               const u32* __restrict__ r2a,
                                               float* __restrict__ out) {
  int t = blockIdx.x * 256 + threadIdx.x;
  u64 k = keys[t];
  int e1 = (int)((k >> 6) & 63), e2 = (int)(k & 63);
  u32 r1 = r1a[t];
  u32 loc2 = cnt1[e2] + r2a[t];
  float2 g = g12[t];
  bool k1 = r1 < (u32)CAP;
  bool k2 = loc2 < (u32)CAP;
  float g1 = k1 ? g.x : 0.f;
  float g2 = k2 ? g.y : 0.f;
  float den = fmaxf(g1 + g2, 1.1920929e-07f);  // np.finfo(f32).eps
  float c1 = g1 / den, c2 = g2 / den;
  float* comb = out + 1;
  float* disp = out + 1 + SEC;
  if (k1) {
    size_t o = ((size_t)t * 64 + e1) * CAP + r1;
    comb[o] = c1;
    disp[o] = 1.0f;
  }
  if (k2) {
    size_t o = ((size_t)t * 64 + e2) * CAP + loc2;
    comb[o] = c2;
    disp[o] = 1.0f;
  }
}

extern "C" void kernel_launch(void* const* d_in, const int* in_sizes, int n_in,
                              void* d_out, int out_size, void* d_ws, size_t ws_size,
                              hipStream_t stream) {
  const float* x = (const float*)d_in[0];
  const float* W = (const float*)d_in[1];
  const float* bias = (const float*)d_in[2];
  float* out = (float*)d_out;

  // workspace layout
  float* Wt = (float*)d_ws;                 // 262144 floats (1 MB)
  float* part = Wt + 262144;                // 4*SS*EE floats (4 MB)
  float* gates = part + 4 * (size_t)SE;     // 262144 floats (1 MB)
  u64* keys = (u64*)(gates + (size_t)SE);   // 4096 u64
  float2* g12 = (float2*)(keys + SS);       // 4096 float2
  u32* cnt1 = (u32*)(g12 + SS);             // 64
  u32* r1a = cnt1 + 64;                     // 4096
  u32* r2a = r1a + SS;                      // 4096
  float* partial = (float*)(r2a + SS);      // 64*64 floats

  hipMemsetAsync(d_out, 0, (size_t)out_size * sizeof(float), stream);
  hipMemsetAsync(cnt1, 0, (64 + 2 * SS) * sizeof(u32), stream);

  k_transpose<<<64, 256, 0, stream>>>(W, Wt);
  k_gemm<<<dim3(64, 4), 256, 0, stream>>>(x, Wt, part);
  k_row<<<SS, 64, 0, stream>>>(part, bias, gates, keys, g12, cnt1);
  k_pair<<<dim3(16, 16), 256, 0, stream>>>(keys, r1a, r2a);
  k_colsum<<<64, 256, 0, stream>>>(gates, partial);
  k_laux2<<<1, 256, 0, stream>>>(partial, cnt1, out);
  k_final<<<16, 256, 0, stream>>>(keys, g12, cnt1, r1a, r2a, out);
}

// Round 3
// 151.315 us; speedup vs baseline: 2.5585x; 1.0076x over previous
//
#include <hip/hip_runtime.h>
#include <hip/hip_bf16.h>
#include <float.h>

#define SS 4096
#define EE 64
#define DD 4096
#define CAP 128
#define SE (SS*EE)                    // 262144
#define ROW 8192                      // EE*CAP floats per token row
static const size_t SEC = (size_t)SS * EE * CAP;  // 33554432

typedef unsigned long long u64;
typedef unsigned int u32;

// ---------------- W transpose + zero flag arrays ----------------
__global__ __launch_bounds__(256) void k_transpose(const float* __restrict__ W,
                                                   float* __restrict__ Wt,
                                                   u32* __restrict__ zbase) {
  // zero cnt1(64) + r1a(4096) + r2a(4096) = 8256 words
  int gid = blockIdx.x * 256 + threadIdx.x;
  if (gid < 64 + 2 * SS) zbase[gid] = 0u;

  __shared__ float t[64][65];
  int k0 = blockIdx.x * 64;
  int tid = threadIdx.x;
#pragma unroll
  for (int i = 0; i < 4; i++) {
    int f = tid + i * 256;
    int e = f >> 4, c4 = f & 15;
    float4 v = *(const float4*)(W + (size_t)e * DD + k0 + c4 * 4);
    t[e][c4 * 4 + 0] = v.x; t[e][c4 * 4 + 1] = v.y;
    t[e][c4 * 4 + 2] = v.z; t[e][c4 * 4 + 3] = v.w;
  }
  __syncthreads();
#pragma unroll
  for (int i = 0; i < 4; i++) {
    int f = tid + i * 256;
    int r = f >> 4, e4 = f & 15;
    float4 o;
    o.x = t[e4 * 4 + 0][r]; o.y = t[e4 * 4 + 1][r];
    o.z = t[e4 * 4 + 2][r]; o.w = t[e4 * 4 + 3][r];
    *(float4*)(Wt + (size_t)(k0 + r) * 64 + e4 * 4) = o;
  }
}

// ---------------- GEMM: part[ks][t][e] = sum_{k in slice} x[t][k]*Wt[k][e] ----------------
__global__ __launch_bounds__(256) void k_gemm(const float* __restrict__ x,
                                              const float* __restrict__ Wt,
                                              float* __restrict__ part) {
  __shared__ float xs[64][68];
  __shared__ float wsh[64][64];
  int tb = blockIdx.x;
  int ks = blockIdx.y;
  int tid = threadIdx.x;
  int tx = tid & 15, ty = tid >> 4;
  float acc[4][4] = {};
  for (int kc = 0; kc < 1024; kc += 64) {
    int k0 = ks * 1024 + kc;
#pragma unroll
    for (int i = 0; i < 4; i++) {
      int f = tid + i * 256;
      int r = f >> 4, c4 = f & 15;
      float4 v = *(const float4*)(x + (size_t)(tb * 64 + r) * DD + k0 + c4 * 4);
      xs[r][c4 * 4 + 0] = v.x; xs[r][c4 * 4 + 1] = v.y;
      xs[r][c4 * 4 + 2] = v.z; xs[r][c4 * 4 + 3] = v.w;
    }
#pragma unroll
    for (int i = 0; i < 4; i++) {
      int f = tid + i * 256;
      int r = f >> 4, c4 = f & 15;
      *(float4*)&wsh[r][c4 * 4] = *(const float4*)(Wt + (size_t)(k0 + r) * 64 + c4 * 4);
    }
    __syncthreads();
#pragma unroll 4
    for (int k4 = 0; k4 < 16; k4++) {
      float xa[4][4], wa[4][4];
#pragma unroll
      for (int i = 0; i < 4; i++) {
        float4 v = *(const float4*)&xs[ty * 4 + i][k4 * 4];
        xa[i][0] = v.x; xa[i][1] = v.y; xa[i][2] = v.z; xa[i][3] = v.w;
      }
#pragma unroll
      for (int kk = 0; kk < 4; kk++) {
        float4 v = *(const float4*)&wsh[k4 * 4 + kk][tx * 4];
        wa[kk][0] = v.x; wa[kk][1] = v.y; wa[kk][2] = v.z; wa[kk][3] = v.w;
      }
#pragma unroll
      for (int i = 0; i < 4; i++)
#pragma unroll
        for (int j = 0; j < 4; j++)
          acc[i][j] += xa[i][0] * wa[0][j] + xa[i][1] * wa[1][j]
                     + xa[i][2] * wa[2][j] + xa[i][3] * wa[3][j];
    }
    __syncthreads();
  }
#pragma unroll
  for (int i = 0; i < 4; i++) {
    float4 o = make_float4(acc[i][0], acc[i][1], acc[i][2], acc[i][3]);
    *(float4*)(part + ((size_t)ks * SS + tb * 64 + ty * 4 + i) * 64 + tx * 4) = o;
  }
}

// ---------------- per-token: softmax, top1 (gates), 2nd (logits), key ----------------
__global__ __launch_bounds__(64) void k_row(const float* __restrict__ part,
                                            const float* __restrict__ bias,
                                            float* __restrict__ gates,
                                            u64* __restrict__ keys,
                                            float2* __restrict__ g12,
                                            u32* __restrict__ cnt1) {
  int t = blockIdx.x;
  int e = threadIdx.x;
  size_t i = (size_t)t * 64 + e;
  float l = part[i] + part[i + (size_t)SE] + part[i + 2 * (size_t)SE]
          + part[i + 3 * (size_t)SE] + bias[e];
  float m = l;
#pragma unroll
  for (int off = 32; off; off >>= 1) m = fmaxf(m, __shfl_xor(m, off));
  float ex = expf(l - m);
  float Z = ex;
#pragma unroll
  for (int off = 32; off; off >>= 1) Z += __shfl_xor(Z, off);
  float gate = ex / Z;
  gates[i] = gate;
  float v1 = gate; int i1 = e;
#pragma unroll
  for (int off = 32; off; off >>= 1) {
    float ov = __shfl_xor(v1, off); int oi = __shfl_xor(i1, off);
    if (ov > v1 || (ov == v1 && oi < i1)) { v1 = ov; i1 = oi; }
  }
  float v2 = (e == i1) ? -FLT_MAX : l; int i2 = e;
#pragma unroll
  for (int off = 32; off; off >>= 1) {
    float ov = __shfl_xor(v2, off); int oi = __shfl_xor(i2, off);
    if (ov > v2 || (ov == v2 && oi < i2)) { v2 = ov; i2 = oi; }
  }
  float g1v = __shfl(gate, i1);
  float g2v = __shfl(gate, i2);
  if (e == 0) {
    u32 gb = __float_as_uint(v1);
    keys[t] = ((u64)(~gb) << 32) | ((u32)t << 12) | ((u32)i1 << 6) | (u32)i2;
    g12[t] = make_float2(g1v, g2v);
    atomicAdd(&cnt1[i1], 1u);
  }
}

// ---------------- pairwise rank counting ----------------
__global__ __launch_bounds__(256) void k_pair(const u64* __restrict__ keys,
                                              u32* __restrict__ r1a,
                                              u32* __restrict__ r2a) {
  __shared__ u64 sk[256];
  int tid = threadIdx.x;
  int t = blockIdx.x * 256 + tid;
  sk[tid] = keys[blockIdx.y * 256 + tid];
  __syncthreads();
  u64 myk = keys[t];
  u32 mye1 = (u32)((myk >> 6) & 63), mye2 = (u32)(myk & 63);
  u32 myt = (u32)t;
  u32 r1 = 0, r2 = 0;
  for (int j = 0; j < 256; j++) {
    u64 ks = sk[j];
    u32 se1 = (u32)((ks >> 6) & 63);
    u32 se2 = (u32)(ks & 63);
    u32 ss = (u32)((ks >> 12) & 4095);
    r1 += (se1 == mye1 && ks < myk) ? 1u : 0u;
    r2 += (se2 == mye2 && ss < myt) ? 1u : 0u;
  }
  if (r1) atomicAdd(&r1a[t], r1);
  if (r2) atomicAdd(&r2a[t], r2);
}

// ---------------- gates column partial sums ----------------
__global__ __launch_bounds__(256) void k_colsum(const float* __restrict__ gates,
                                                float* __restrict__ partial) {
  __shared__ float sh[256];
  int b = blockIdx.x;
  int tid = threadIdx.x;
  int lane = tid & 63, w = tid >> 6;
  float s = 0.f;
#pragma unroll
  for (int i = 0; i < 16; i++) {
    int t = b * 64 + w * 16 + i;
    s += gates[(size_t)t * 64 + lane];
  }
  sh[tid] = s;
  __syncthreads();
  if (tid < 64) {
    float p = sh[tid] + sh[tid + 64] + sh[tid + 128] + sh[tid + 192];
    partial[b * 64 + tid] = p;
  }
}

// ---------------- l_aux combine (writes to workspace slot) ----------------
__global__ __launch_bounds__(256) void k_laux2(const float* __restrict__ partial,
                                               const u32* __restrict__ cnt1,
                                               float* __restrict__ lauxp) {
  __shared__ float sh[256];
  int tid = threadIdx.x;
  int e = tid & 63, q = tid >> 6;
  float s = 0.f;
#pragma unroll
  for (int b = 0; b < 16; b++) s += partial[(q * 16 + b) * 64 + e];
  sh[tid] = s;
  __syncthreads();
  if (tid < 64) {
    float colsum = sh[tid] + sh[tid + 64] + sh[tid + 128] + sh[tid + 192];
    float me = colsum * (1.0f / SS);
    float ce = (float)cnt1[tid] * (1.0f / SS);
    float term = me * ce;
#pragma unroll
    for (int off = 32; off; off >>= 1) term += __shfl_xor(term, off);
    if (tid == 0) lauxp[0] = term * (float)EE * 0.01f;
  }
}

// ---------------- token slot info ----------------
__device__ __forceinline__ void load_tok(int tok,
    const u64* __restrict__ keys, const float2* __restrict__ g12,
    const u32* __restrict__ cnt1, const u32* __restrict__ r1a,
    const u32* __restrict__ r2a, int& o1, float& c1, int& o2, float& c2) {
  u64 k = keys[tok];
  int e1 = (int)((k >> 6) & 63), e2 = (int)(k & 63);
  u32 r1 = r1a[tok];
  u32 loc2 = cnt1[e2] + r2a[tok];
  float2 g = g12[tok];
  bool k1 = r1 < (u32)CAP;
  bool k2 = loc2 < (u32)CAP;
  float g1 = k1 ? g.x : 0.f;
  float g2 = k2 ? g.y : 0.f;
  float den = fmaxf(g1 + g2, 1.1920929e-07f);
  c1 = g1 / den;
  c2 = g2 / den;
  o1 = k1 ? e1 * CAP + (int)r1 : -1;
  o2 = k2 ? e2 * CAP + (int)loc2 : -1;
}

// ---------------- fused zero-fill + scatter (writes ALL of d_out) ----------------
// Blocks 0..4095: comb region, block t covers out[t*8192 .. (t+1)*8192)
//   (lidx 0 = prev token's slot 8191 / l_aux for block 0; lidx j+1 = token t slot j)
// Blocks 4096..8191: disp region, same structure shifted by SEC.
// Tail element out[2*SEC] written by block 8191 thread 0.
__global__ __launch_bounds__(256) void k_fill(const u64* __restrict__ keys,
                                              const float2* __restrict__ g12,
                                              const u32* __restrict__ cnt1,
                                              const u32* __restrict__ r1a,
                                              const u32* __restrict__ r2a,
                                              const float* __restrict__ lauxp,
                                              float* __restrict__ out) {
  int b = blockIdx.x;
  int tid = threadIdx.x;
  bool isDisp = b >= SS;
  int t = isDisp ? b - SS : b;

  int o1, o2; float c1, c2;
  load_tok(t, keys, g12, cnt1, r1a, r2a, o1, c1, o2, c2);
  float v1 = isDisp ? 1.f : c1;
  float v2 = isDisp ? 1.f : c2;

  int p0 = -1, p1 = -1, p2 = -1;
  float q0 = 0.f, q1 = 0.f, q2 = 0.f;
  if (o1 >= 0 && o1 < ROW - 1) { p0 = o1 + 1; q0 = v1; }
  if (o2 >= 0 && o2 < ROW - 1) { p1 = o2 + 1; q1 = v2; }

  if (b == 0) {
    p2 = 0; q2 = lauxp[0];
  } else {
    // lidx 0 holds slot 8191 of the previous region row
    bool prevIsComb = (!isDisp) || (b == SS);  // disp block 0's lidx 0 = comb token 4095
    int tprev = (b == SS) ? SS - 1 : t - 1;
    int po1, po2; float pc1, pc2;
    load_tok(tprev, keys, g12, cnt1, r1a, r2a, po1, pc1, po2, pc2);
    if (po1 == ROW - 1)      { p2 = 0; q2 = prevIsComb ? pc1 : 1.f; }
    else if (po2 == ROW - 1) { p2 = 0; q2 = prevIsComb ? pc2 : 1.f; }
  }

  float* dst = out + (size_t)b * ROW;
#pragma unroll
  for (int i = 0; i < 8; i++) {
    int l0 = (tid + i * 256) * 4;
    float4 v;
    int la = l0, lb = l0 + 1, lc = l0 + 2, ld = l0 + 3;
    v.x = (la == p0) ? q0 : (la == p1) ? q1 : (la == p2) ? q2 : 0.f;
    v.y = (lb == p0) ? q0 : (lb == p1) ? q1 : (lb == p2) ? q2 : 0.f;
    v.z = (lc == p0) ? q0 : (lc == p1) ? q1 : (lc == p2) ? q2 : 0.f;
    v.w = (ld == p0) ? q0 : (ld == p1) ? q1 : (ld == p2) ? q2 : 0.f;
    *(float4*)(dst + l0) = v;
  }

  if (b == 2 * SS - 1 && tid == 0) {
    // last disp element: token 4095, slot 8191
    float tv = (o1 == ROW - 1 || o2 == ROW - 1) ? 1.f : 0.f;
    out[2 * SEC] = tv;
  }
}

extern "C" void kernel_launch(void* const* d_in, const int* in_sizes, int n_in,
                              void* d_out, int out_size, void* d_ws, size_t ws_size,
                              hipStream_t stream) {
  const float* x = (const float*)d_in[0];
  const float* W = (const float*)d_in[1];
  const float* bias = (const float*)d_in[2];
  float* out = (float*)d_out;

  // workspace layout
  float* Wt = (float*)d_ws;                 // 262144 floats (1 MB)
  float* part = Wt + 262144;                // 4*SS*EE floats (4 MB)
  float* gates = part + 4 * (size_t)SE;     // 262144 floats (1 MB)
  u64* keys = (u64*)(gates + (size_t)SE);   // 4096 u64
  float2* g12 = (float2*)(keys + SS);       // 4096 float2
  u32* cnt1 = (u32*)(g12 + SS);             // 64
  u32* r1a = cnt1 + 64;                     // 4096
  u32* r2a = r1a + SS;                      // 4096
  float* partial = (float*)(r2a + SS);      // 64*64 floats
  float* lauxp = partial + 64 * 64;         // 1 float

  k_transpose<<<64, 256, 0, stream>>>(W, Wt, cnt1);
  k_gemm<<<dim3(64, 4), 256, 0, stream>>>(x, Wt, part);
  k_row<<<SS, 64, 0, stream>>>(part, bias, gates, keys, g12, cnt1);
  k_pair<<<dim3(16, 16), 256, 0, stream>>>(keys, r1a, r2a);
  k_colsum<<<64, 256, 0, stream>>>(gates, partial);
  k_laux2<<<1, 256, 0, stream>>>(partial, cnt1, lauxp);
  k_fill<<<2 * SS, 256, 0, stream>>>(keys, g12, cnt1, r1a, r2a, lauxp, out);
}